// Round 4
// baseline (271.810 us; speedup 1.0000x reference)
//
#include <hip/hip_runtime.h>
#include <hip/hip_bf16.h>
#include <hip/hip_fp16.h>

#define EPS 1e-8f

// Kernel 0: convert both f32 emb tables to f16 in workspace.
__global__ __launch_bounds__(256) void convert_f16_kernel(
    const float2* __restrict__ emb1, const float2* __restrict__ emb2,
    __half2* __restrict__ h1, __half2* __restrict__ h2, int n2)
{
    int i = blockIdx.x * blockDim.x + threadIdx.x;
    if (i < n2) {
        float2 a = emb1[i];
        float2 b = emb2[i];
        h1[i] = __floats2half2_rn(a.x, a.y);
        h2[i] = __floats2half2_rn(b.x, b.y);
    }
}

__device__ __forceinline__ float dot16_h4(uint4 A0, uint4 A1, uint4 B0, uint4 B1) {
    const __half2* a0 = (const __half2*)&A0;
    const __half2* a1 = (const __half2*)&A1;
    const __half2* b0 = (const __half2*)&B0;
    const __half2* b1 = (const __half2*)&B1;
    float acc = 0.0f;
#pragma unroll
    for (int i = 0; i < 4; ++i) {
        float2 fa = __half22float2(a0[i]);
        float2 fb = __half22float2(b0[i]);
        acc += fa.x * fb.x + fa.y * fb.y;
        float2 ga = __half22float2(a1[i]);
        float2 gb = __half22float2(b1[i]);
        acc += ga.x * gb.x + ga.y * gb.y;
    }
    return acc;
}

__device__ __forceinline__ float sigmoidf_(float x) {
    return 1.0f / (1.0f + __expf(-x));
}

// Pass 1: 2 edges/thread. All 8 row-b128 loads issued independently up front
// (4 concurrent random gathers/thread -> 2x the MLP of R3's version).
__global__ __launch_bounds__(256) void edge_w_kernel(
    const int* __restrict__ src, const int* __restrict__ dst,
    const uint4* __restrict__ h1, const uint4* __restrict__ h2,  // f16 rows: 2x uint4 per row
    __half2* __restrict__ w2, float* __restrict__ row_sum, int n_edges)
{
    int t = blockIdx.x * blockDim.x + threadIdx.x;
    int e0 = t * 2;
    if (e0 + 1 < n_edges) {
        int2 s = ((const int2*)src)[t];
        int2 d = ((const int2*)dst)[t];
        const uint4* pa0 = h1 + (size_t)s.x * 2;
        const uint4* pa1 = h1 + (size_t)s.y * 2;
        const uint4* pb0 = h2 + (size_t)d.x * 2;
        const uint4* pb1 = h2 + (size_t)d.y * 2;
        // 8 independent 16B loads — compiler should issue all before waitcnt
        uint4 A00 = pa0[0], A01 = pa0[1];
        uint4 B00 = pb0[0], B01 = pb0[1];
        uint4 A10 = pa1[0], A11 = pa1[1];
        uint4 B10 = pb1[0], B11 = pb1[1];

        float w0 = sigmoidf_(dot16_h4(A00, A01, B00, B01));
        float w1 = sigmoidf_(dot16_h4(A10, A11, B10, B11));

        w2[t] = __floats2half2_rn(w0, w1);
        atomicAdd(&row_sum[s.x], w0);
        atomicAdd(&row_sum[s.y], w1);
    } else if (e0 < n_edges) {
        // odd tail: single edge
        int s = src[e0], d = dst[e0];
        const uint4* pa = h1 + (size_t)s * 2;
        const uint4* pb = h2 + (size_t)d * 2;
        uint4 A0 = pa[0], A1 = pa[1], B0 = pb[0], B1 = pb[1];
        float wv = sigmoidf_(dot16_h4(A0, A1, B0, B1));
        ((__half*)w2)[e0] = __float2half(wv);
        atomicAdd(&row_sum[s], wv);
    }
}

// Pass 2: 4 edges/thread. row_sum is 400KB -> L2-resident; 4 independent gathers.
__global__ __launch_bounds__(256) void edge_norm_kernel(
    const int* __restrict__ src, const __half* __restrict__ w,
    const float* __restrict__ row_sum, float* __restrict__ out, int n_edges)
{
    int t = blockIdx.x * blockDim.x + threadIdx.x;
    int e0 = t * 4;
    if (e0 + 3 < n_edges) {
        int4 s = ((const int4*)src)[t];
        uint2 wraw = ((const uint2*)w)[t];  // 4 halves
        float r0 = row_sum[s.x];
        float r1 = row_sum[s.y];
        float r2 = row_sum[s.z];
        float r3 = row_sum[s.w];
        const __half2* wh = (const __half2*)&wraw;
        float2 w01 = __half22float2(wh[0]);
        float2 w23 = __half22float2(wh[1]);
        float4 o;
        o.x = w01.x / (r0 + EPS);
        o.y = w01.y / (r1 + EPS);
        o.z = w23.x / (r2 + EPS);
        o.w = w23.y / (r3 + EPS);
        ((float4*)out)[t] = o;
    } else if (e0 < n_edges) {
        for (int e = e0; e < n_edges; ++e) {
            out[e] = __half2float(w[e]) / (row_sum[src[e]] + EPS);
        }
    }
}

extern "C" void kernel_launch(void* const* d_in, const int* in_sizes, int n_in,
                              void* d_out, int out_size, void* d_ws, size_t ws_size,
                              hipStream_t stream) {
    const int*   src  = (const int*)d_in[0];
    const int*   dst  = (const int*)d_in[1];
    const float* emb1 = (const float*)d_in[2];
    const float* emb2 = (const float*)d_in[3];
    float* out = (float*)d_out;

    int n_edges = in_sizes[0];
    int n_emb   = in_sizes[2];          // N_NODES * 16 floats
    int n_nodes = n_emb / 16;

    // ws layout (16B-aligned chunks):
    //   row_sum : n_nodes f32  (400 KB)
    //   w       : n_edges f16  (6.4 MB)
    //   h1, h2  : n_emb f16    (3.2 MB each)
    char* base = (char*)d_ws;
    float*   row_sum = (float*)base;
    size_t off = ((size_t)n_nodes * sizeof(float) + 15) & ~(size_t)15;
    __half*  w = (__half*)(base + off);
    off += ((size_t)n_edges * sizeof(__half) + 15) & ~(size_t)15;
    __half2* h1 = (__half2*)(base + off);
    off += ((size_t)n_emb * sizeof(__half) + 15) & ~(size_t)15;
    __half2* h2 = (__half2*)(base + off);

    hipMemsetAsync(row_sum, 0, (size_t)n_nodes * sizeof(float), stream);

    int block = 256;
    int n2 = n_emb / 2;
    convert_f16_kernel<<<(n2 + block - 1) / block, block, 0, stream>>>(
        (const float2*)emb1, (const float2*)emb2, h1, h2, n2);

    int n_pair = (n_edges + 1) / 2;
    edge_w_kernel<<<(n_pair + block - 1) / block, block, 0, stream>>>(
        src, dst, (const uint4*)h1, (const uint4*)h2, (__half2*)w, row_sum, n_edges);

    int n_quad = (n_edges + 3) / 4;
    edge_norm_kernel<<<(n_quad + block - 1) / block, block, 0, stream>>>(
        src, w, row_sum, out, n_edges);
}

// Round 5
// 265.553 us; speedup vs baseline: 1.0236x; 1.0236x over previous
//
#include <hip/hip_runtime.h>
#include <hip/hip_bf16.h>
#include <hip/hip_fp16.h>

#define EPS 1e-8f
#define NXCD 8

// Kernel 0: convert both f32 emb tables to f16 in workspace.
__global__ __launch_bounds__(256) void convert_f16_kernel(
    const float2* __restrict__ emb1, const float2* __restrict__ emb2,
    __half2* __restrict__ h1, __half2* __restrict__ h2, int n2)
{
    int i = blockIdx.x * blockDim.x + threadIdx.x;
    if (i < n2) {
        float2 a = emb1[i];
        float2 b = emb2[i];
        h1[i] = __floats2half2_rn(a.x, a.y);
        h2[i] = __floats2half2_rn(b.x, b.y);
    }
}

__device__ __forceinline__ float dot16_h4(uint4 A0, uint4 A1, uint4 B0, uint4 B1) {
    const __half2* a0 = (const __half2*)&A0;
    const __half2* a1 = (const __half2*)&A1;
    const __half2* b0 = (const __half2*)&B0;
    const __half2* b1 = (const __half2*)&B1;
    float acc = 0.0f;
#pragma unroll
    for (int i = 0; i < 4; ++i) {
        float2 fa = __half22float2(a0[i]);
        float2 fb = __half22float2(b0[i]);
        acc += fa.x * fb.x + fa.y * fb.y;
        float2 ga = __half22float2(a1[i]);
        float2 gb = __half22float2(b1[i]);
        acc += ga.x * gb.x + ga.y * gb.y;
    }
    return acc;
}

__device__ __forceinline__ float sigmoidf_(float x) {
    return 1.0f / (1.0f + __expf(-x));
}

__device__ __forceinline__ unsigned xcc_id() {
    unsigned x;
    asm volatile("s_getreg_b32 %0, hwreg(HW_REG_XCC_ID)" : "=s"(x));
    return x & (NXCD - 1);
}

// Pass 1 (replicated): per-XCD row_sum replica, workgroup-scope atomics that
// execute at the local (per-XCD) TCC and get absorbed in L2 instead of being
// forwarded to the memory-side coherence point.
__global__ __launch_bounds__(256) void edge_w_rep_kernel(
    const int* __restrict__ src, const int* __restrict__ dst,
    const uint4* __restrict__ h1, const uint4* __restrict__ h2,
    __half2* __restrict__ w2, float* __restrict__ rep, int n_edges, int n_nodes)
{
    float* my = rep + (size_t)xcc_id() * n_nodes;

    int t = blockIdx.x * blockDim.x + threadIdx.x;
    int e0 = t * 2;
    if (e0 + 1 < n_edges) {
        int2 s = ((const int2*)src)[t];
        int2 d = ((const int2*)dst)[t];
        const uint4* pa0 = h1 + (size_t)s.x * 2;
        const uint4* pa1 = h1 + (size_t)s.y * 2;
        const uint4* pb0 = h2 + (size_t)d.x * 2;
        const uint4* pb1 = h2 + (size_t)d.y * 2;
        uint4 A00 = pa0[0], A01 = pa0[1];
        uint4 B00 = pb0[0], B01 = pb0[1];
        uint4 A10 = pa1[0], A11 = pa1[1];
        uint4 B10 = pb1[0], B11 = pb1[1];

        float w0 = sigmoidf_(dot16_h4(A00, A01, B00, B01));
        float w1 = sigmoidf_(dot16_h4(A10, A11, B10, B11));

        w2[t] = __floats2half2_rn(w0, w1);
        __hip_atomic_fetch_add(&my[s.x], w0, __ATOMIC_RELAXED, __HIP_MEMORY_SCOPE_WORKGROUP);
        __hip_atomic_fetch_add(&my[s.y], w1, __ATOMIC_RELAXED, __HIP_MEMORY_SCOPE_WORKGROUP);
    } else if (e0 < n_edges) {
        int s = src[e0], d = dst[e0];
        const uint4* pa = h1 + (size_t)s * 2;
        const uint4* pb = h2 + (size_t)d * 2;
        uint4 A0 = pa[0], A1 = pa[1], B0 = pb[0], B1 = pb[1];
        float wv = sigmoidf_(dot16_h4(A0, A1, B0, B1));
        ((__half*)w2)[e0] = __float2half(wv);
        __hip_atomic_fetch_add(&my[s], wv, __ATOMIC_RELAXED, __HIP_MEMORY_SCOPE_WORKGROUP);
    }
}

// Pass 1 (fallback, agent-scope atomics on a single table) if ws too small.
__global__ __launch_bounds__(256) void edge_w_kernel(
    const int* __restrict__ src, const int* __restrict__ dst,
    const uint4* __restrict__ h1, const uint4* __restrict__ h2,
    __half2* __restrict__ w2, float* __restrict__ row_sum, int n_edges)
{
    int t = blockIdx.x * blockDim.x + threadIdx.x;
    int e0 = t * 2;
    if (e0 + 1 < n_edges) {
        int2 s = ((const int2*)src)[t];
        int2 d = ((const int2*)dst)[t];
        const uint4* pa0 = h1 + (size_t)s.x * 2;
        const uint4* pa1 = h1 + (size_t)s.y * 2;
        const uint4* pb0 = h2 + (size_t)d.x * 2;
        const uint4* pb1 = h2 + (size_t)d.y * 2;
        uint4 A00 = pa0[0], A01 = pa0[1];
        uint4 B00 = pb0[0], B01 = pb0[1];
        uint4 A10 = pa1[0], A11 = pa1[1];
        uint4 B10 = pb1[0], B11 = pb1[1];
        float w0 = sigmoidf_(dot16_h4(A00, A01, B00, B01));
        float w1 = sigmoidf_(dot16_h4(A10, A11, B10, B11));
        w2[t] = __floats2half2_rn(w0, w1);
        atomicAdd(&row_sum[s.x], w0);
        atomicAdd(&row_sum[s.y], w1);
    } else if (e0 < n_edges) {
        int s = src[e0], d = dst[e0];
        const uint4* pa = h1 + (size_t)s * 2;
        const uint4* pb = h2 + (size_t)d * 2;
        uint4 A0 = pa[0], A1 = pa[1], B0 = pb[0], B1 = pb[1];
        float wv = sigmoidf_(dot16_h4(A0, A1, B0, B1));
        ((__half*)w2)[e0] = __float2half(wv);
        atomicAdd(&row_sum[s], wv);
    }
}

// Fold: row_sum[n] = sum over 8 replicas. 4 nodes/thread via float4.
__global__ __launch_bounds__(256) void fold_kernel(
    const float* __restrict__ rep, float* __restrict__ row_sum, int n_nodes)
{
    int t = blockIdx.x * blockDim.x + threadIdx.x;
    int n0 = t * 4;
    if (n0 >= n_nodes) return;
    if (n0 + 3 < n_nodes) {
        float4 acc = ((const float4*)(rep))[t];
#pragma unroll
        for (int x = 1; x < NXCD; ++x) {
            float4 v = *(const float4*)(rep + (size_t)x * n_nodes + n0);
            acc.x += v.x; acc.y += v.y; acc.z += v.z; acc.w += v.w;
        }
        ((float4*)row_sum)[t] = acc;
    } else {
        for (int n = n0; n < n_nodes; ++n) {
            float a = 0.0f;
            for (int x = 0; x < NXCD; ++x) a += rep[(size_t)x * n_nodes + n];
            row_sum[n] = a;
        }
    }
}

// Pass 2: 4 edges/thread normalize.
__global__ __launch_bounds__(256) void edge_norm_kernel(
    const int* __restrict__ src, const __half* __restrict__ w,
    const float* __restrict__ row_sum, float* __restrict__ out, int n_edges)
{
    int t = blockIdx.x * blockDim.x + threadIdx.x;
    int e0 = t * 4;
    if (e0 + 3 < n_edges) {
        int4 s = ((const int4*)src)[t];
        uint2 wraw = ((const uint2*)w)[t];
        float r0 = row_sum[s.x];
        float r1 = row_sum[s.y];
        float r2 = row_sum[s.z];
        float r3 = row_sum[s.w];
        const __half2* wh = (const __half2*)&wraw;
        float2 w01 = __half22float2(wh[0]);
        float2 w23 = __half22float2(wh[1]);
        float4 o;
        o.x = w01.x / (r0 + EPS);
        o.y = w01.y / (r1 + EPS);
        o.z = w23.x / (r2 + EPS);
        o.w = w23.y / (r3 + EPS);
        ((float4*)out)[t] = o;
    } else if (e0 < n_edges) {
        for (int e = e0; e < n_edges; ++e) {
            out[e] = __half2float(w[e]) / (row_sum[src[e]] + EPS);
        }
    }
}

extern "C" void kernel_launch(void* const* d_in, const int* in_sizes, int n_in,
                              void* d_out, int out_size, void* d_ws, size_t ws_size,
                              hipStream_t stream) {
    const int*   src  = (const int*)d_in[0];
    const int*   dst  = (const int*)d_in[1];
    const float* emb1 = (const float*)d_in[2];
    const float* emb2 = (const float*)d_in[3];
    float* out = (float*)d_out;

    int n_edges = in_sizes[0];
    int n_emb   = in_sizes[2];          // N_NODES * 16 floats
    int n_nodes = n_emb / 16;

    // ws layout (16B-aligned chunks):
    //   rep     : NXCD * n_nodes f32   (3.2 MB)   [replicated path only]
    //   row_sum : n_nodes f32          (400 KB)
    //   w       : n_edges f16          (6.4 MB)
    //   h1, h2  : n_emb f16            (3.2 MB each)
    size_t sz_rep = ((size_t)NXCD * n_nodes * sizeof(float) + 15) & ~(size_t)15;
    size_t sz_rs  = ((size_t)n_nodes * sizeof(float) + 15) & ~(size_t)15;
    size_t sz_w   = ((size_t)n_edges * sizeof(__half) + 15) & ~(size_t)15;
    size_t sz_h   = ((size_t)n_emb * sizeof(__half) + 15) & ~(size_t)15;
    bool replicated = ws_size >= sz_rep + sz_rs + sz_w + 2 * sz_h;

    char* base = (char*)d_ws;
    float* rep = (float*)base;
    size_t off = replicated ? sz_rep : 0;
    float*   row_sum = (float*)(base + off); off += sz_rs;
    __half*  w  = (__half*)(base + off);     off += sz_w;
    __half2* h1 = (__half2*)(base + off);    off += sz_h;
    __half2* h2 = (__half2*)(base + off);

    int block = 256;
    int n2 = n_emb / 2;
    convert_f16_kernel<<<(n2 + block - 1) / block, block, 0, stream>>>(
        (const float2*)emb1, (const float2*)emb2, h1, h2, n2);

    int n_pair = (n_edges + 1) / 2;
    int grid_w = (n_pair + block - 1) / block;
    if (replicated) {
        hipMemsetAsync(rep, 0, (size_t)NXCD * n_nodes * sizeof(float), stream);
        edge_w_rep_kernel<<<grid_w, block, 0, stream>>>(
            src, dst, (const uint4*)h1, (const uint4*)h2, (__half2*)w, rep,
            n_edges, n_nodes);
        int n_quad_n = (n_nodes + 3) / 4;
        fold_kernel<<<(n_quad_n + block - 1) / block, block, 0, stream>>>(
            rep, row_sum, n_nodes);
    } else {
        hipMemsetAsync(row_sum, 0, (size_t)n_nodes * sizeof(float), stream);
        edge_w_kernel<<<grid_w, block, 0, stream>>>(
            src, dst, (const uint4*)h1, (const uint4*)h2, (__half2*)w, row_sum,
            n_edges);
    }

    int n_quad = (n_edges + 3) / 4;
    edge_norm_kernel<<<(n_quad + block - 1) / block, block, 0, stream>>>(
        src, w, row_sum, out, n_edges);
}